// Round 3
// baseline (150.239 us; speedup 1.0000x reference)
//
#include <hip/hip_runtime.h>
#include <math.h>

#define BB 64
#define AA 8732
#define DD 85
#define GG 32
#define CC 81
#define TILE 64
#define NT 137   /* ceil(8732/64) */
#define NAB 35   /* ceil(8732/256) stage-A blocks */

// ---------------- workspace layout (bytes) ----------------
// match:       0          .. 2235392   (B*A int32)
// n_pos:       2235392    .. 2235648   (B int32)
// all_neg:     2235648    .. 4471040   (B*A float)
// partials:    4471040    .. 4506112   (B*NT float)
// batch_total: 4506112    .. 4506368   (B float)
// bestp:       4506368    .. 4514560   (B*G int32)

__device__ __forceinline__ float smoothl1(float d) {
  float ad = fabsf(d);
  return ad < 1.0f ? 0.5f * d * d : ad - 0.5f;
}

// Fused matcher. grid (NAB+GG, B), 256 threads.
//  blocks [0,NAB):   stage A — per-anchor best GT (threshold), first-max-wins
//  blocks [NAB,+GG): stage B — per-GT best anchor (forced match argmax)
// block (0,b) also zeroes n_pos[b] (accumulated later by k_loss via atomicAdd).
__global__ __launch_bounds__(256) void k_match(
    const float* __restrict__ anchors, const float* __restrict__ gt_boxes,
    const int* __restrict__ gt_counts, int* __restrict__ match,
    int* __restrict__ bestp, int* __restrict__ n_pos)
{
  const int b = blockIdx.y;
  const int count = gt_counts[b];
  __shared__ float gx0[GG], gy0[GG], gx1[GG], gy1[GG], gar[GG];
  __shared__ float wv[4];
  __shared__ int wi[4];

  if (blockIdx.x < NAB) {
    if (blockIdx.x == 0 && threadIdx.x == 0) n_pos[b] = 0;
    if (threadIdx.x < GG) {
      float4 gb = reinterpret_cast<const float4*>(gt_boxes)[b * GG + threadIdx.x];
      float x0 = gb.x - gb.z * 0.5f, y0 = gb.y - gb.w * 0.5f;
      float x1 = gb.x + gb.z * 0.5f, y1 = gb.y + gb.w * 0.5f;
      gx0[threadIdx.x] = x0; gy0[threadIdx.x] = y0;
      gx1[threadIdx.x] = x1; gy1[threadIdx.x] = y1;
      gar[threadIdx.x] = (x1 - x0) * (y1 - y0);
    }
    __syncthreads();
    const int a = blockIdx.x * 256 + threadIdx.x;
    if (a >= AA) return;

    float4 an = reinterpret_cast<const float4*>(anchors)[a];
    float ax0 = an.x - an.z * 0.5f, ay0 = an.y - an.w * 0.5f;
    float ax1 = an.x + an.z * 0.5f, ay1 = an.y + an.w * 0.5f;
    float aar = (ax1 - ax0) * (ay1 - ay0);
    float best = -1.0f; int bi = 0;
    for (int g = 0; g < count; ++g) {
      float iw = fmaxf(fminf(gx1[g], ax1) - fmaxf(gx0[g], ax0), 0.0f);
      float ih = fmaxf(fminf(gy1[g], ay1) - fmaxf(gy0[g], ay0), 0.0f);
      float inter = iw * ih;
      float iou = inter / (gar[g] + aar - inter);
      if (iou > best) { best = iou; bi = g; }   // first max wins
    }
    match[b * AA + a] = (best > 0.5f) ? bi : -1;
  } else {
    const int g = blockIdx.x - NAB;
    if (g >= count) return;

    float4 gb = reinterpret_cast<const float4*>(gt_boxes)[b * GG + g];
    const float gx0s = gb.x - gb.z * 0.5f, gy0s = gb.y - gb.w * 0.5f;
    const float gx1s = gb.x + gb.z * 0.5f, gy1s = gb.y + gb.w * 0.5f;
    const float gars = (gx1s - gx0s) * (gy1s - gy0s);

    float bv = -2.0f; int bi = AA;
    for (int a = threadIdx.x; a < AA; a += 256) {
      float4 an = reinterpret_cast<const float4*>(anchors)[a];
      float ax0 = an.x - an.z * 0.5f, ay0 = an.y - an.w * 0.5f;
      float ax1 = an.x + an.z * 0.5f, ay1 = an.y + an.w * 0.5f;
      float aar = (ax1 - ax0) * (ay1 - ay0);
      float iw = fmaxf(fminf(gx1s, ax1) - fmaxf(gx0s, ax0), 0.0f);
      float ih = fmaxf(fminf(gy1s, ay1) - fmaxf(gy0s, ay0), 0.0f);
      float inter = iw * ih;
      float iou = inter / (gars + aar - inter);
      if (iou > bv || (iou == bv && a < bi)) { bv = iou; bi = a; }
    }
    #pragma unroll
    for (int m = 1; m < 64; m <<= 1) {
      float ov = __shfl_xor(bv, m);
      int   oi = __shfl_xor(bi, m);
      if (ov > bv || (ov == bv && oi < bi)) { bv = ov; bi = oi; }
    }
    if ((threadIdx.x & 63) == 0) { wv[threadIdx.x >> 6] = bv; wi[threadIdx.x >> 6] = bi; }
    __syncthreads();
    if (threadIdx.x == 0) {
      float fv = wv[0]; int fi = wi[0];
      #pragma unroll
      for (int w = 1; w < 4; ++w)
        if (wv[w] > fv || (wv[w] == fv && wi[w] < fi)) { fv = wv[w]; fi = wi[w]; }
      bestp[b * GG + g] = fi;
    }
  }
}

// Heavy pass: grid (NT, B), 256 threads, 4 threads/row.
// Folds the forced-match override (bestp, ascending g = last-write-wins)
// and the n_pos count (integer atomicAdd, order-independent) into this pass.
// Softmax is branch-free two-pass (max sweep, then exp-sum sweep) over LDS.
__global__ __launch_bounds__(256) void k_loss(
    const float* __restrict__ pred, const float* __restrict__ anchors,
    const float* __restrict__ gt_boxes, const int* __restrict__ gt_labels,
    const int* __restrict__ gt_counts, const int* __restrict__ match,
    const int* __restrict__ bestp, float* __restrict__ all_neg,
    float* __restrict__ partials, int* __restrict__ n_pos)
{
  const int b = blockIdx.y;
  const int tile = blockIdx.x;
  const int a0 = tile * TILE;
  const int nrows = min(TILE, AA - a0);
  __shared__ float rows[TILE * DD];
  __shared__ float wsum[4];
  __shared__ int wcnt[4];
  __shared__ int sbp[GG];
  __shared__ int scount;

  if (threadIdx.x == 0) scount = gt_counts[b];
  if (threadIdx.x < GG) sbp[threadIdx.x] = bestp[b * GG + threadIdx.x];

  const float* src = pred + ((size_t)b * AA + a0) * DD;
  const int n4 = (nrows * DD) >> 2;   // nrows*85 divisible by 4 for 64 and 28
  const float4* src4 = reinterpret_cast<const float4*>(src);
  float4* dst4 = reinterpret_cast<float4*>(rows);
  for (int i = threadIdx.x; i < n4; i += 256) dst4[i] = src4[i];
  __syncthreads();

  const int r = threadIdx.x >> 2;
  const int sub = threadIdx.x & 3;
  float acc = 0.0f;
  int posflag = 0;
  if (r < nrows) {
    const int a = a0 + r;
    int m = match[b * AA + a];
    const int cnt = scount;
    for (int g = 0; g < cnt; ++g)
      if (sbp[g] == a) m = g;          // ascending g = last-write-wins
    const int tgt = (m >= 0) ? gt_labels[b * GG + m] + 1 : 0;

    const float* row = rows + r * DD + 4;
    float mx = -INFINITY, x0 = -INFINITY, xt = -INFINITY;
    for (int cc = sub; cc < CC; cc += 4) {
      float x = row[cc];
      if (cc == 0)   x0 = x;
      if (cc == tgt) xt = x;
      mx = fmaxf(mx, x);
    }
    #pragma unroll
    for (int msk = 1; msk <= 2; msk <<= 1) {
      mx = fmaxf(mx, __shfl_xor(mx, msk));
      x0 = fmaxf(x0, __shfl_xor(x0, msk));
      xt = fmaxf(xt, __shfl_xor(xt, msk));
    }
    float s = 0.0f;
    for (int cc = sub; cc < CC; cc += 4) s += expf(row[cc] - mx);
    #pragma unroll
    for (int msk = 1; msk <= 2; msk <<= 1) s += __shfl_xor(s, msk);
    const float lse = mx + logf(s);

    if (sub == 0) {
      if (m >= 0) {
        posflag = 1;
        float cls_ce = lse - xt;
        float4 an = reinterpret_cast<const float4*>(anchors)[a];
        float4 gb = reinterpret_cast<const float4*>(gt_boxes)[b * GG + m];
        float tx = (gb.x - an.x) / an.z;
        float ty = (gb.y - an.y) / an.w;
        float tw = logf(gb.z) - logf(an.z);
        float th = logf(gb.w) - logf(an.w);
        acc = smoothl1(rows[r * DD + 0] - tx)
            + smoothl1(rows[r * DD + 1] - ty)
            + smoothl1(rows[r * DD + 2] - tw)
            + smoothl1(rows[r * DD + 3] - th)
            + cls_ce;
        all_neg[b * AA + a] = 0.0f;
      } else {
        float ce = lse - x0;            // tgt==0 for negatives
        all_neg[b * AA + a] = fmaxf(ce, 0.0f);
      }
    }
  }

  #pragma unroll
  for (int msk = 1; msk < 64; msk <<= 1) {
    acc     += __shfl_xor(acc, msk);
    posflag += __shfl_xor(posflag, msk);
  }
  if ((threadIdx.x & 63) == 0) {
    wsum[threadIdx.x >> 6] = acc;
    wcnt[threadIdx.x >> 6] = posflag;
  }
  __syncthreads();
  if (threadIdx.x == 0) {
    partials[b * NT + tile] = (wsum[0] + wsum[1]) + (wsum[2] + wsum[3]);
    int c = wcnt[0] + wcnt[1] + wcnt[2] + wcnt[3];
    if (c) atomicAdd(&n_pos[b], c);    // integer add: order-independent
  }
}

// ---- per-batch top-K sum via 4-round radix select (exact K-th largest) ----
__global__ __launch_bounds__(1024) void k_select(
    const float* __restrict__ all_neg, const float* __restrict__ partials,
    const int* __restrict__ n_pos, float* __restrict__ batch_total)
{
  const int b = blockIdx.x;
  __shared__ unsigned u[AA];
  __shared__ int hist[256];
  __shared__ int gsum[64];
  __shared__ unsigned sh_pref;
  __shared__ int sh_k;
  __shared__ float wf[16];
  __shared__ int wc[16];

  const uint4* src = reinterpret_cast<const uint4*>(all_neg + (size_t)b * AA);
  for (int i = threadIdx.x; i < AA / 4; i += 1024)
    reinterpret_cast<uint4*>(u)[i] = src[i];
  __syncthreads();

  const int np = n_pos[b];
  const int K = min(3 * np, AA - 1);

  unsigned prefix = 0;
  int kk = K;
  for (int shift = 24; shift >= 0; shift -= 8) {
    if (threadIdx.x < 256) hist[threadIdx.x] = 0;
    __syncthreads();
    const unsigned hmask = (shift == 24) ? 0u : (0xFFFFFFFFu << (shift + 8));
    for (int i = threadIdx.x; i < AA; i += 1024) {
      unsigned x = u[i];
      if ((x & hmask) == prefix)
        atomicAdd(&hist[(x >> shift) & 255], 1);
    }
    __syncthreads();
    if (threadIdx.x < 64) {
      int base = 255 - 4 * threadIdx.x;
      gsum[threadIdx.x] = hist[base] + hist[base - 1] + hist[base - 2] + hist[base - 3];
    }
    __syncthreads();
    if (threadIdx.x == 0) {
      int cum = 0, chosen = 0;
      const int kv = kk;
      for (int t = 0; t < 64; ++t) {
        int gs = gsum[t];
        if (cum + gs < kv) { cum += gs; continue; }
        for (int bin = 255 - 4 * t; bin >= 252 - 4 * t; --bin) {
          int h = hist[bin];
          if (cum + h >= kv) { chosen = bin; break; }
          cum += h;
        }
        break;
      }
      sh_pref = prefix | ((unsigned)chosen << shift);
      sh_k = kk - cum;
    }
    __syncthreads();
    prefix = sh_pref;
    kk = sh_k;
    __syncthreads();
  }
  const float tstar = __uint_as_float(prefix);   // exact K-th largest

  float ssum = 0.0f; int cgt = 0;
  for (int i = threadIdx.x; i < AA; i += 1024) {
    float x = __uint_as_float(u[i]);
    if (x > tstar) { ssum += x; cgt += 1; }
  }
  #pragma unroll
  for (int m = 1; m < 64; m <<= 1) {
    ssum += __shfl_xor(ssum, m);
    cgt  += __shfl_xor(cgt, m);
  }
  if ((threadIdx.x & 63) == 0) { wf[threadIdx.x >> 6] = ssum; wc[threadIdx.x >> 6] = cgt; }
  __syncthreads();
  if (threadIdx.x == 0) {
    float S = 0.0f; int Cg = 0;
    for (int w = 0; w < 16; ++w) { S += wf[w]; Cg += wc[w]; }
    float neg_sum = S + (float)(K - Cg) * tstar;
    float ps = 0.0f;
    for (int t = 0; t < NT; ++t) ps += partials[b * NT + t];
    batch_total[b] = (ps + neg_sum) / (float)np;
  }
}

__global__ __launch_bounds__(64) void k_final(
    const float* __restrict__ batch_total, float* __restrict__ out)
{
  float v = batch_total[threadIdx.x];   // BB == 64 == one wave
  #pragma unroll
  for (int m = 1; m < 64; m <<= 1) v += __shfl_xor(v, m);
  if (threadIdx.x == 0) out[0] = v;
}

extern "C" void kernel_launch(void* const* d_in, const int* in_sizes, int n_in,
                              void* d_out, int out_size, void* d_ws, size_t ws_size,
                              hipStream_t stream) {
  (void)in_sizes; (void)n_in; (void)out_size; (void)ws_size;
  const float* pred      = (const float*)d_in[0];
  const float* anchors   = (const float*)d_in[1];
  const float* gt_boxes  = (const float*)d_in[2];
  const int*   gt_labels = (const int*)d_in[3];
  const int*   gt_counts = (const int*)d_in[4];

  char* ws = (char*)d_ws;
  int*   match       = (int*)(ws + 0);
  int*   n_pos       = (int*)(ws + 2235392);
  float* all_neg     = (float*)(ws + 2235648);
  float* partials    = (float*)(ws + 4471040);
  float* batch_total = (float*)(ws + 4506112);
  int*   bestp       = (int*)(ws + 4506368);
  float* out = (float*)d_out;

  hipLaunchKernelGGL(k_match, dim3(NAB + GG, BB), dim3(256), 0, stream,
                     anchors, gt_boxes, gt_counts, match, bestp, n_pos);
  hipLaunchKernelGGL(k_loss, dim3(NT, BB), dim3(256), 0, stream,
                     pred, anchors, gt_boxes, gt_labels, gt_counts, match, bestp,
                     all_neg, partials, n_pos);
  hipLaunchKernelGGL(k_select, dim3(BB), dim3(1024), 0, stream,
                     all_neg, partials, n_pos, batch_total);
  hipLaunchKernelGGL(k_final, dim3(1), dim3(64), 0, stream, batch_total, out);
}

// Round 4
// 146.222 us; speedup vs baseline: 1.0275x; 1.0275x over previous
//
#include <hip/hip_runtime.h>
#include <math.h>

#define BB 64
#define AA 8732
#define DD 85
#define GG 32
#define CC 81
#define TILE 64
#define NT 137   /* ceil(8732/64) */
#define NAB 35   /* ceil(8732/256) stage-A blocks */

// ---------------- workspace layout (bytes) ----------------
// match:       0          .. 2235392   (B*A int32)
// n_pos:       2235392    .. 2235648   (B int32)
// all_neg:     2235648    .. 4471040   (B*A float)
// partials:    4471040    .. 4506112   (B*NT float)
// batch_total: 4506112    .. 4506368   (B float)
// bestp:       4506368    .. 4514560   (B*G int32)

__device__ __forceinline__ float smoothl1(float d) {
  float ad = fabsf(d);
  return ad < 1.0f ? 0.5f * d * d : ad - 0.5f;
}

__device__ __forceinline__ float frcp(float x) {
  return __builtin_amdgcn_rcpf(x);
}

// Fused matcher. grid (NAB+GG, B), 256 threads.
//  blocks [0,NAB):   stage A — per-anchor best GT (threshold), first-max-wins
//  blocks [NAB,+GG): stage B — per-GT best anchor (forced match argmax)
// block (0,b) also zeroes n_pos[b] (accumulated later by k_loss via atomicAdd).
__global__ __launch_bounds__(256) void k_match(
    const float* __restrict__ anchors, const float* __restrict__ gt_boxes,
    const int* __restrict__ gt_counts, int* __restrict__ match,
    int* __restrict__ bestp, int* __restrict__ n_pos)
{
  const int b = blockIdx.y;
  const int count = gt_counts[b];
  __shared__ float gx0[GG], gy0[GG], gx1[GG], gy1[GG], gar[GG];
  __shared__ float wv[4];
  __shared__ int wi[4];

  if (blockIdx.x < NAB) {
    if (blockIdx.x == 0 && threadIdx.x == 0) n_pos[b] = 0;
    if (threadIdx.x < GG) {
      float4 gb = reinterpret_cast<const float4*>(gt_boxes)[b * GG + threadIdx.x];
      float x0 = gb.x - gb.z * 0.5f, y0 = gb.y - gb.w * 0.5f;
      float x1 = gb.x + gb.z * 0.5f, y1 = gb.y + gb.w * 0.5f;
      gx0[threadIdx.x] = x0; gy0[threadIdx.x] = y0;
      gx1[threadIdx.x] = x1; gy1[threadIdx.x] = y1;
      gar[threadIdx.x] = (x1 - x0) * (y1 - y0);
    }
    __syncthreads();
    const int a = blockIdx.x * 256 + threadIdx.x;
    if (a >= AA) return;

    float4 an = reinterpret_cast<const float4*>(anchors)[a];
    float ax0 = an.x - an.z * 0.5f, ay0 = an.y - an.w * 0.5f;
    float ax1 = an.x + an.z * 0.5f, ay1 = an.y + an.w * 0.5f;
    float aar = (ax1 - ax0) * (ay1 - ay0);
    float best = -1.0f; int bi = 0;
    for (int g = 0; g < count; ++g) {
      float iw = fmaxf(fminf(gx1[g], ax1) - fmaxf(gx0[g], ax0), 0.0f);
      float ih = fmaxf(fminf(gy1[g], ay1) - fmaxf(gy0[g], ay0), 0.0f);
      float inter = iw * ih;
      float iou = inter * frcp(gar[g] + aar - inter);
      if (iou > best) { best = iou; bi = g; }   // first max wins
    }
    match[b * AA + a] = (best > 0.5f) ? bi : -1;
  } else {
    const int g = blockIdx.x - NAB;
    if (g >= count) return;

    float4 gb = reinterpret_cast<const float4*>(gt_boxes)[b * GG + g];
    const float gx0s = gb.x - gb.z * 0.5f, gy0s = gb.y - gb.w * 0.5f;
    const float gx1s = gb.x + gb.z * 0.5f, gy1s = gb.y + gb.w * 0.5f;
    const float gars = (gx1s - gx0s) * (gy1s - gy0s);

    float bv = -2.0f; int bi = AA;
    for (int a = threadIdx.x; a < AA; a += 256) {
      float4 an = reinterpret_cast<const float4*>(anchors)[a];
      float ax0 = an.x - an.z * 0.5f, ay0 = an.y - an.w * 0.5f;
      float ax1 = an.x + an.z * 0.5f, ay1 = an.y + an.w * 0.5f;
      float aar = (ax1 - ax0) * (ay1 - ay0);
      float iw = fmaxf(fminf(gx1s, ax1) - fmaxf(gx0s, ax0), 0.0f);
      float ih = fmaxf(fminf(gy1s, ay1) - fmaxf(gy0s, ay0), 0.0f);
      float inter = iw * ih;
      float iou = inter * frcp(gars + aar - inter);
      if (iou > bv || (iou == bv && a < bi)) { bv = iou; bi = a; }
    }
    #pragma unroll
    for (int m = 1; m < 64; m <<= 1) {
      float ov = __shfl_xor(bv, m);
      int   oi = __shfl_xor(bi, m);
      if (ov > bv || (ov == bv && oi < bi)) { bv = ov; bi = oi; }
    }
    if ((threadIdx.x & 63) == 0) { wv[threadIdx.x >> 6] = bv; wi[threadIdx.x >> 6] = bi; }
    __syncthreads();
    if (threadIdx.x == 0) {
      float fv = wv[0]; int fi = wi[0];
      #pragma unroll
      for (int w = 1; w < 4; ++w)
        if (wv[w] > fv || (wv[w] == fv && wi[w] < fi)) { fv = wv[w]; fi = wi[w]; }
      bestp[b * GG + g] = fi;
    }
  }
}

// Heavy pass: grid (NT, B), 256 threads, 4 threads/row.
// One LDS sweep with register cache (v[21], fully unrolled -> VGPRs),
// fast __expf/__logf, forced-match override via LDS atomicMax scatter.
__global__ __launch_bounds__(256) void k_loss(
    const float* __restrict__ pred, const float* __restrict__ anchors,
    const float* __restrict__ gt_boxes, const int* __restrict__ gt_labels,
    const int* __restrict__ gt_counts, const int* __restrict__ match,
    const int* __restrict__ bestp, float* __restrict__ all_neg,
    float* __restrict__ partials, int* __restrict__ n_pos)
{
  const int b = blockIdx.y;
  const int tile = blockIdx.x;
  const int a0 = tile * TILE;
  const int nrows = min(TILE, AA - a0);
  __shared__ float rows[TILE * DD];
  __shared__ int ovr[TILE];
  __shared__ float wsum[4];
  __shared__ int wcnt[4];

  // stage tile (coalesced float4) + init override slots
  const float* src = pred + ((size_t)b * AA + a0) * DD;
  const int n4 = (nrows * DD) >> 2;   // nrows*85 divisible by 4 for 64 and 28
  const float4* src4 = reinterpret_cast<const float4*>(src);
  float4* dst4 = reinterpret_cast<float4*>(rows);
  for (int i = threadIdx.x; i < n4; i += 256) dst4[i] = src4[i];
  if (threadIdx.x < TILE) ovr[threadIdx.x] = -1;
  __syncthreads();

  // forced-match scatter into this tile (max g == ascending last-write-wins)
  if (threadIdx.x < GG) {
    if (threadIdx.x < gt_counts[b]) {
      int p = bestp[b * GG + threadIdx.x];
      if (p >= a0 && p < a0 + nrows) atomicMax(&ovr[p - a0], threadIdx.x);
    }
  }
  __syncthreads();

  const int r = threadIdx.x >> 2;
  const int sub = threadIdx.x & 3;
  float acc = 0.0f;
  int posflag = 0;
  if (r < nrows) {
    const int a = a0 + r;
    int m = ovr[r];
    if (m < 0) m = match[b * AA + a];
    const int tgt = (m >= 0) ? gt_labels[b * GG + m] + 1 : 0;

    const float* row = rows + r * DD + 4;
    float v[21];
    float mx = -INFINITY, x0 = -INFINITY, xt = -INFINITY;
    #pragma unroll
    for (int k = 0; k < 21; ++k) {
      const int cc = 4 * k + sub;
      float x = (cc < CC) ? row[cc] : -INFINITY;
      v[k] = x;
      if (cc == 0)   x0 = x;
      if (cc == tgt) xt = x;
      mx = fmaxf(mx, x);
    }
    #pragma unroll
    for (int msk = 1; msk <= 2; msk <<= 1) {
      mx = fmaxf(mx, __shfl_xor(mx, msk));
      x0 = fmaxf(x0, __shfl_xor(x0, msk));
      xt = fmaxf(xt, __shfl_xor(xt, msk));
    }
    float s = 0.0f;
    #pragma unroll
    for (int k = 0; k < 21; ++k) s += __expf(v[k] - mx);   // exp(-inf)=0 pads
    #pragma unroll
    for (int msk = 1; msk <= 2; msk <<= 1) s += __shfl_xor(s, msk);
    const float lse = mx + __logf(s);

    if (sub == 0) {
      if (m >= 0) {
        posflag = 1;
        float cls_ce = lse - xt;
        float4 an = reinterpret_cast<const float4*>(anchors)[a];
        float4 gb = reinterpret_cast<const float4*>(gt_boxes)[b * GG + m];
        float tx = (gb.x - an.x) / an.z;
        float ty = (gb.y - an.y) / an.w;
        float tw = __logf(gb.z) - __logf(an.z);
        float th = __logf(gb.w) - __logf(an.w);
        acc = smoothl1(rows[r * DD + 0] - tx)
            + smoothl1(rows[r * DD + 1] - ty)
            + smoothl1(rows[r * DD + 2] - tw)
            + smoothl1(rows[r * DD + 3] - th)
            + cls_ce;
        all_neg[b * AA + a] = 0.0f;
      } else {
        float ce = lse - x0;            // tgt==0 for negatives
        all_neg[b * AA + a] = fmaxf(ce, 0.0f);
      }
    }
  }

  #pragma unroll
  for (int msk = 1; msk < 64; msk <<= 1) {
    acc     += __shfl_xor(acc, msk);
    posflag += __shfl_xor(posflag, msk);
  }
  if ((threadIdx.x & 63) == 0) {
    wsum[threadIdx.x >> 6] = acc;
    wcnt[threadIdx.x >> 6] = posflag;
  }
  __syncthreads();
  if (threadIdx.x == 0) {
    partials[b * NT + tile] = (wsum[0] + wsum[1]) + (wsum[2] + wsum[3]);
    int c = wcnt[0] + wcnt[1] + wcnt[2] + wcnt[3];
    if (c) atomicAdd(&n_pos[b], c);    // integer add: order-independent
  }
}

// ---- per-batch top-K sum via 4-round radix select (exact K-th largest) ----
__global__ __launch_bounds__(1024) void k_select(
    const float* __restrict__ all_neg, const float* __restrict__ partials,
    const int* __restrict__ n_pos, float* __restrict__ batch_total)
{
  const int b = blockIdx.x;
  __shared__ unsigned u[AA];
  __shared__ int hist[256];
  __shared__ int gsum[64];
  __shared__ unsigned sh_pref;
  __shared__ int sh_k;
  __shared__ float wf[16];
  __shared__ int wc[16];

  const uint4* src = reinterpret_cast<const uint4*>(all_neg + (size_t)b * AA);
  for (int i = threadIdx.x; i < AA / 4; i += 1024)
    reinterpret_cast<uint4*>(u)[i] = src[i];
  __syncthreads();

  const int np = n_pos[b];
  const int K = min(3 * np, AA - 1);

  unsigned prefix = 0;
  int kk = K;
  for (int shift = 24; shift >= 0; shift -= 8) {
    if (threadIdx.x < 256) hist[threadIdx.x] = 0;
    __syncthreads();
    const unsigned hmask = (shift == 24) ? 0u : (0xFFFFFFFFu << (shift + 8));
    for (int i = threadIdx.x; i < AA; i += 1024) {
      unsigned x = u[i];
      if ((x & hmask) == prefix)
        atomicAdd(&hist[(x >> shift) & 255], 1);
    }
    __syncthreads();
    if (threadIdx.x < 64) {
      int base = 255 - 4 * threadIdx.x;
      gsum[threadIdx.x] = hist[base] + hist[base - 1] + hist[base - 2] + hist[base - 3];
    }
    __syncthreads();
    if (threadIdx.x == 0) {
      int cum = 0, chosen = 0;
      const int kv = kk;
      for (int t = 0; t < 64; ++t) {
        int gs = gsum[t];
        if (cum + gs < kv) { cum += gs; continue; }
        for (int bin = 255 - 4 * t; bin >= 252 - 4 * t; --bin) {
          int h = hist[bin];
          if (cum + h >= kv) { chosen = bin; break; }
          cum += h;
        }
        break;
      }
      sh_pref = prefix | ((unsigned)chosen << shift);
      sh_k = kk - cum;
    }
    __syncthreads();
    prefix = sh_pref;
    kk = sh_k;
    __syncthreads();
  }
  const float tstar = __uint_as_float(prefix);   // exact K-th largest

  float ssum = 0.0f; int cgt = 0;
  for (int i = threadIdx.x; i < AA; i += 1024) {
    float x = __uint_as_float(u[i]);
    if (x > tstar) { ssum += x; cgt += 1; }
  }
  #pragma unroll
  for (int m = 1; m < 64; m <<= 1) {
    ssum += __shfl_xor(ssum, m);
    cgt  += __shfl_xor(cgt, m);
  }
  if ((threadIdx.x & 63) == 0) { wf[threadIdx.x >> 6] = ssum; wc[threadIdx.x >> 6] = cgt; }
  __syncthreads();
  if (threadIdx.x == 0) {
    float S = 0.0f; int Cg = 0;
    for (int w = 0; w < 16; ++w) { S += wf[w]; Cg += wc[w]; }
    float neg_sum = S + (float)(K - Cg) * tstar;
    float ps = 0.0f;
    for (int t = 0; t < NT; ++t) ps += partials[b * NT + t];
    batch_total[b] = (ps + neg_sum) / (float)np;
  }
}

__global__ __launch_bounds__(64) void k_final(
    const float* __restrict__ batch_total, float* __restrict__ out)
{
  float v = batch_total[threadIdx.x];   // BB == 64 == one wave
  #pragma unroll
  for (int m = 1; m < 64; m <<= 1) v += __shfl_xor(v, m);
  if (threadIdx.x == 0) out[0] = v;
}

extern "C" void kernel_launch(void* const* d_in, const int* in_sizes, int n_in,
                              void* d_out, int out_size, void* d_ws, size_t ws_size,
                              hipStream_t stream) {
  (void)in_sizes; (void)n_in; (void)out_size; (void)ws_size;
  const float* pred      = (const float*)d_in[0];
  const float* anchors   = (const float*)d_in[1];
  const float* gt_boxes  = (const float*)d_in[2];
  const int*   gt_labels = (const int*)d_in[3];
  const int*   gt_counts = (const int*)d_in[4];

  char* ws = (char*)d_ws;
  int*   match       = (int*)(ws + 0);
  int*   n_pos       = (int*)(ws + 2235392);
  float* all_neg     = (float*)(ws + 2235648);
  float* partials    = (float*)(ws + 4471040);
  float* batch_total = (float*)(ws + 4506112);
  int*   bestp       = (int*)(ws + 4506368);
  float* out = (float*)d_out;

  hipLaunchKernelGGL(k_match, dim3(NAB + GG, BB), dim3(256), 0, stream,
                     anchors, gt_boxes, gt_counts, match, bestp, n_pos);
  hipLaunchKernelGGL(k_loss, dim3(NT, BB), dim3(256), 0, stream,
                     pred, anchors, gt_boxes, gt_labels, gt_counts, match, bestp,
                     all_neg, partials, n_pos);
  hipLaunchKernelGGL(k_select, dim3(BB), dim3(1024), 0, stream,
                     all_neg, partials, n_pos, batch_total);
  hipLaunchKernelGGL(k_final, dim3(1), dim3(64), 0, stream, batch_total, out);
}

// Round 5
// 129.970 us; speedup vs baseline: 1.1560x; 1.1250x over previous
//
#include <hip/hip_runtime.h>
#include <math.h>

#define BB 64
#define AA 8732
#define DD 85
#define GG 32
#define CC 81
#define TILE 64
#define NT 137   /* ceil(8732/64) */
#define NAB 35   /* ceil(8732/256) stage-A blocks */

// ---------------- workspace layout (bytes) ----------------
// match:       0          .. 2235392   (B*A int32)
// n_pos:       2235392    .. 2235648   (B int32)
// all_neg:     2235648    .. 4471040   (B*A float)
// partials:    4471040    .. 4506112   (B*NT float)
// batch_total: 4506112    .. 4506368   (B float)
// bestp:       4506368    .. 4514560   (B*G int32)

typedef __attribute__((address_space(3))) unsigned int lds_u32;
typedef const __attribute__((address_space(1))) unsigned int glb_u32;

__device__ __forceinline__ float smoothl1(float d) {
  float ad = fabsf(d);
  return ad < 1.0f ? 0.5f * d * d : ad - 0.5f;
}

__device__ __forceinline__ float frcp(float x) {
  return __builtin_amdgcn_rcpf(x);
}

// Fused matcher. grid (NAB+GG, B), 256 threads.
__global__ __launch_bounds__(256) void k_match(
    const float* __restrict__ anchors, const float* __restrict__ gt_boxes,
    const int* __restrict__ gt_counts, int* __restrict__ match,
    int* __restrict__ bestp, int* __restrict__ n_pos)
{
  const int b = blockIdx.y;
  const int count = gt_counts[b];
  __shared__ float gx0[GG], gy0[GG], gx1[GG], gy1[GG], gar[GG];
  __shared__ float wv[4];
  __shared__ int wi[4];

  if (blockIdx.x < NAB) {
    if (blockIdx.x == 0 && threadIdx.x == 0) n_pos[b] = 0;
    if (threadIdx.x < GG) {
      float4 gb = reinterpret_cast<const float4*>(gt_boxes)[b * GG + threadIdx.x];
      float x0 = gb.x - gb.z * 0.5f, y0 = gb.y - gb.w * 0.5f;
      float x1 = gb.x + gb.z * 0.5f, y1 = gb.y + gb.w * 0.5f;
      gx0[threadIdx.x] = x0; gy0[threadIdx.x] = y0;
      gx1[threadIdx.x] = x1; gy1[threadIdx.x] = y1;
      gar[threadIdx.x] = (x1 - x0) * (y1 - y0);
    }
    __syncthreads();
    const int a = blockIdx.x * 256 + threadIdx.x;
    if (a >= AA) return;

    float4 an = reinterpret_cast<const float4*>(anchors)[a];
    float ax0 = an.x - an.z * 0.5f, ay0 = an.y - an.w * 0.5f;
    float ax1 = an.x + an.z * 0.5f, ay1 = an.y + an.w * 0.5f;
    float aar = (ax1 - ax0) * (ay1 - ay0);
    float best = -1.0f; int bi = 0;
    for (int g = 0; g < count; ++g) {
      float iw = fmaxf(fminf(gx1[g], ax1) - fmaxf(gx0[g], ax0), 0.0f);
      float ih = fmaxf(fminf(gy1[g], ay1) - fmaxf(gy0[g], ay0), 0.0f);
      float inter = iw * ih;
      float iou = inter * frcp(gar[g] + aar - inter);
      if (iou > best) { best = iou; bi = g; }   // first max wins
    }
    match[b * AA + a] = (best > 0.5f) ? bi : -1;
  } else {
    const int g = blockIdx.x - NAB;
    if (g >= count) return;

    float4 gb = reinterpret_cast<const float4*>(gt_boxes)[b * GG + g];
    const float gx0s = gb.x - gb.z * 0.5f, gy0s = gb.y - gb.w * 0.5f;
    const float gx1s = gb.x + gb.z * 0.5f, gy1s = gb.y + gb.w * 0.5f;
    const float gars = (gx1s - gx0s) * (gy1s - gy0s);

    float bv = -2.0f; int bi = AA;
    for (int a = threadIdx.x; a < AA; a += 256) {
      float4 an = reinterpret_cast<const float4*>(anchors)[a];
      float ax0 = an.x - an.z * 0.5f, ay0 = an.y - an.w * 0.5f;
      float ax1 = an.x + an.z * 0.5f, ay1 = an.y + an.w * 0.5f;
      float aar = (ax1 - ax0) * (ay1 - ay0);
      float iw = fmaxf(fminf(gx1s, ax1) - fmaxf(gx0s, ax0), 0.0f);
      float ih = fmaxf(fminf(gy1s, ay1) - fmaxf(gy0s, ay0), 0.0f);
      float inter = iw * ih;
      float iou = inter * frcp(gars + aar - inter);
      if (iou > bv || (iou == bv && a < bi)) { bv = iou; bi = a; }
    }
    #pragma unroll
    for (int m = 1; m < 64; m <<= 1) {
      float ov = __shfl_xor(bv, m);
      int   oi = __shfl_xor(bi, m);
      if (ov > bv || (ov == bv && oi < bi)) { bv = ov; bi = oi; }
    }
    if ((threadIdx.x & 63) == 0) { wv[threadIdx.x >> 6] = bv; wi[threadIdx.x >> 6] = bi; }
    __syncthreads();
    if (threadIdx.x == 0) {
      float fv = wv[0]; int fi = wi[0];
      #pragma unroll
      for (int w = 1; w < 4; ++w)
        if (wv[w] > fv || (wv[w] == fv && wi[w] < fi)) { fv = wv[w]; fi = wi[w]; }
      bestp[b * GG + g] = fi;
    }
  }
}

// Heavy pass: grid (NT, B), 256 threads, 4 threads/row.
// Staging via global_load_lds (fire-and-forget direct global->LDS; the
// __syncthreads drain replaces the VGPR roundtrip -> ~6KB in flight per wave
// instead of 96B -> memory system saturates).
__global__ __launch_bounds__(256) void k_loss(
    const float* __restrict__ pred, const float* __restrict__ anchors,
    const float* __restrict__ gt_boxes, const int* __restrict__ gt_labels,
    const int* __restrict__ gt_counts, const int* __restrict__ match,
    const int* __restrict__ bestp, float* __restrict__ all_neg,
    float* __restrict__ partials, int* __restrict__ n_pos)
{
  const int b = blockIdx.y;
  const int tile = blockIdx.x;
  const int a0 = tile * TILE;
  const int nrows = min(TILE, AA - a0);
  __shared__ float rows[TILE * DD];
  __shared__ int ovr[TILE];
  __shared__ float wsum[4];
  __shared__ int wcnt[4];

  // direct global->LDS staging: 16B chunks, linear in wave-lane order.
  {
    const int nchunks = (nrows * DD) >> 2;    // 1360 full tile, 595 tail
    const float* srcg = pred + ((size_t)b * AA + a0) * DD;   // 16B-aligned
    #pragma unroll
    for (int j = 0; j < 6; ++j) {
      int c = j * 256 + threadIdx.x;
      if (c < nchunks) {
        __builtin_amdgcn_global_load_lds(
            (glb_u32*)(srcg + c * 4), (lds_u32*)(rows + c * 4), 16, 0, 0);
      }
    }
  }
  if (threadIdx.x < TILE) ovr[threadIdx.x] = -1;
  __syncthreads();   // drains vmcnt -> tile resident

  // forced-match scatter into this tile (max g == ascending last-write-wins)
  if (threadIdx.x < GG) {
    if (threadIdx.x < gt_counts[b]) {
      int p = bestp[b * GG + threadIdx.x];
      if (p >= a0 && p < a0 + nrows) atomicMax(&ovr[p - a0], threadIdx.x);
    }
  }
  __syncthreads();

  const int r = threadIdx.x >> 2;
  const int sub = threadIdx.x & 3;
  float acc = 0.0f;
  int posflag = 0;
  if (r < nrows) {
    const int a = a0 + r;
    int m = ovr[r];
    if (m < 0) m = match[b * AA + a];
    const int tgt = (m >= 0) ? gt_labels[b * GG + m] + 1 : 0;

    const float* row = rows + r * DD + 4;
    float v[21];
    float mx = -INFINITY, x0 = -INFINITY, xt = -INFINITY;
    #pragma unroll
    for (int k = 0; k < 21; ++k) {
      const int cc = 4 * k + sub;
      float x = (cc < CC) ? row[cc] : -INFINITY;
      v[k] = x;
      if (cc == 0)   x0 = x;
      if (cc == tgt) xt = x;
      mx = fmaxf(mx, x);
    }
    #pragma unroll
    for (int msk = 1; msk <= 2; msk <<= 1) {
      mx = fmaxf(mx, __shfl_xor(mx, msk));
      x0 = fmaxf(x0, __shfl_xor(x0, msk));
      xt = fmaxf(xt, __shfl_xor(xt, msk));
    }
    float s = 0.0f;
    #pragma unroll
    for (int k = 0; k < 21; ++k) s += __expf(v[k] - mx);   // exp(-inf)=0 pads
    #pragma unroll
    for (int msk = 1; msk <= 2; msk <<= 1) s += __shfl_xor(s, msk);
    const float lse = mx + __logf(s);

    if (sub == 0) {
      if (m >= 0) {
        posflag = 1;
        float cls_ce = lse - xt;
        float4 an = reinterpret_cast<const float4*>(anchors)[a];
        float4 gb = reinterpret_cast<const float4*>(gt_boxes)[b * GG + m];
        float tx = (gb.x - an.x) / an.z;
        float ty = (gb.y - an.y) / an.w;
        float tw = __logf(gb.z) - __logf(an.z);
        float th = __logf(gb.w) - __logf(an.w);
        acc = smoothl1(rows[r * DD + 0] - tx)
            + smoothl1(rows[r * DD + 1] - ty)
            + smoothl1(rows[r * DD + 2] - tw)
            + smoothl1(rows[r * DD + 3] - th)
            + cls_ce;
        all_neg[b * AA + a] = 0.0f;
      } else {
        float ce = lse - x0;            // tgt==0 for negatives
        all_neg[b * AA + a] = fmaxf(ce, 0.0f);
      }
    }
  }

  #pragma unroll
  for (int msk = 1; msk < 64; msk <<= 1) {
    acc     += __shfl_xor(acc, msk);
    posflag += __shfl_xor(posflag, msk);
  }
  if ((threadIdx.x & 63) == 0) {
    wsum[threadIdx.x >> 6] = acc;
    wcnt[threadIdx.x >> 6] = posflag;
  }
  __syncthreads();
  if (threadIdx.x == 0) {
    partials[b * NT + tile] = (wsum[0] + wsum[1]) + (wsum[2] + wsum[3]);
    int c = wcnt[0] + wcnt[1] + wcnt[2] + wcnt[3];
    if (c) atomicAdd(&n_pos[b], c);    // integer add: order-independent
  }
}

// ---- per-batch top-K sum via 4-round radix select (exact K-th largest) ----
// global_load_lds staging + 16 per-wave histograms (stride 257 -> bank shift)
__global__ __launch_bounds__(1024) void k_select(
    const float* __restrict__ all_neg, const float* __restrict__ partials,
    const int* __restrict__ n_pos, float* __restrict__ batch_total)
{
  const int b = blockIdx.x;
  __shared__ unsigned u[AA];           // 34928 B
  __shared__ int hist16[16][257];      // 16448 B, per-wave
  __shared__ int hist[256];
  __shared__ int gsum[64];
  __shared__ unsigned sh_pref;
  __shared__ int sh_k;
  __shared__ float wf[16];
  __shared__ int wc[16];

  // stage 8732 floats = 2183 x 16B chunks, fire-and-forget
  {
    const float* srcg = all_neg + (size_t)b * AA;   // 16B-aligned
    #pragma unroll
    for (int j = 0; j < 3; ++j) {
      int c = j * 1024 + threadIdx.x;
      if (c < 2183) {
        __builtin_amdgcn_global_load_lds(
            (glb_u32*)(srcg + c * 4), (lds_u32*)((float*)u + c * 4), 16, 0, 0);
      }
    }
  }
  __syncthreads();

  const int np = n_pos[b];
  const int K = min(3 * np, AA - 1);
  const int wvid = threadIdx.x >> 6;

  unsigned prefix = 0;
  int kk = K;
  for (int shift = 24; shift >= 0; shift -= 8) {
    int* hflat = &hist16[0][0];
    for (int i = threadIdx.x; i < 16 * 257; i += 1024) hflat[i] = 0;
    __syncthreads();
    const unsigned hmask = (shift == 24) ? 0u : (0xFFFFFFFFu << (shift + 8));
    for (int i = threadIdx.x; i < AA; i += 1024) {
      unsigned x = u[i];
      if ((x & hmask) == prefix)
        atomicAdd(&hist16[wvid][(x >> shift) & 255], 1);
    }
    __syncthreads();
    if (threadIdx.x < 256) {
      int s = 0;
      #pragma unroll
      for (int h = 0; h < 16; ++h) s += hist16[h][threadIdx.x];
      hist[threadIdx.x] = s;
    }
    __syncthreads();
    if (threadIdx.x < 64) {
      int base = 255 - 4 * threadIdx.x;
      gsum[threadIdx.x] = hist[base] + hist[base - 1] + hist[base - 2] + hist[base - 3];
    }
    __syncthreads();
    if (threadIdx.x == 0) {
      int cum = 0, chosen = 0;
      const int kv = kk;
      for (int t = 0; t < 64; ++t) {
        int gs = gsum[t];
        if (cum + gs < kv) { cum += gs; continue; }
        for (int bin = 255 - 4 * t; bin >= 252 - 4 * t; --bin) {
          int h = hist[bin];
          if (cum + h >= kv) { chosen = bin; break; }
          cum += h;
        }
        break;
      }
      sh_pref = prefix | ((unsigned)chosen << shift);
      sh_k = kk - cum;
    }
    __syncthreads();
    prefix = sh_pref;
    kk = sh_k;
    __syncthreads();
  }
  const float tstar = __uint_as_float(prefix);   // exact K-th largest

  float ssum = 0.0f; int cgt = 0;
  for (int i = threadIdx.x; i < AA; i += 1024) {
    float x = __uint_as_float(u[i]);
    if (x > tstar) { ssum += x; cgt += 1; }
  }
  #pragma unroll
  for (int m = 1; m < 64; m <<= 1) {
    ssum += __shfl_xor(ssum, m);
    cgt  += __shfl_xor(cgt, m);
  }
  if ((threadIdx.x & 63) == 0) { wf[wvid] = ssum; wc[wvid] = cgt; }
  __syncthreads();
  if (threadIdx.x == 0) {
    float S = 0.0f; int Cg = 0;
    for (int w = 0; w < 16; ++w) { S += wf[w]; Cg += wc[w]; }
    float neg_sum = S + (float)(K - Cg) * tstar;
    float ps = 0.0f;
    for (int t = 0; t < NT; ++t) ps += partials[b * NT + t];
    batch_total[b] = (ps + neg_sum) / (float)np;
  }
}

__global__ __launch_bounds__(64) void k_final(
    const float* __restrict__ batch_total, float* __restrict__ out)
{
  float v = batch_total[threadIdx.x];   // BB == 64 == one wave
  #pragma unroll
  for (int m = 1; m < 64; m <<= 1) v += __shfl_xor(v, m);
  if (threadIdx.x == 0) out[0] = v;
}

extern "C" void kernel_launch(void* const* d_in, const int* in_sizes, int n_in,
                              void* d_out, int out_size, void* d_ws, size_t ws_size,
                              hipStream_t stream) {
  (void)in_sizes; (void)n_in; (void)out_size; (void)ws_size;
  const float* pred      = (const float*)d_in[0];
  const float* anchors   = (const float*)d_in[1];
  const float* gt_boxes  = (const float*)d_in[2];
  const int*   gt_labels = (const int*)d_in[3];
  const int*   gt_counts = (const int*)d_in[4];

  char* ws = (char*)d_ws;
  int*   match       = (int*)(ws + 0);
  int*   n_pos       = (int*)(ws + 2235392);
  float* all_neg     = (float*)(ws + 2235648);
  float* partials    = (float*)(ws + 4471040);
  float* batch_total = (float*)(ws + 4506112);
  int*   bestp       = (int*)(ws + 4506368);
  float* out = (float*)d_out;

  hipLaunchKernelGGL(k_match, dim3(NAB + GG, BB), dim3(256), 0, stream,
                     anchors, gt_boxes, gt_counts, match, bestp, n_pos);
  hipLaunchKernelGGL(k_loss, dim3(NT, BB), dim3(256), 0, stream,
                     pred, anchors, gt_boxes, gt_labels, gt_counts, match, bestp,
                     all_neg, partials, n_pos);
  hipLaunchKernelGGL(k_select, dim3(BB), dim3(1024), 0, stream,
                     all_neg, partials, n_pos, batch_total);
  hipLaunchKernelGGL(k_final, dim3(1), dim3(64), 0, stream, batch_total, out);
}

// Round 6
// 101.275 us; speedup vs baseline: 1.4835x; 1.2833x over previous
//
#include <hip/hip_runtime.h>
#include <math.h>

#define BB 64
#define AA 8732
#define DD 85
#define GG 32
#define CC 81
#define TILE 64
#define NT 137   /* ceil(8732/64) tiles */
#define TPB 4    /* tiles per k_loss block */
#define NTB 35   /* ceil(NT/TPB) = k_loss grid.x */
#define NAB 35   /* ceil(8732/256) stage-A blocks in k_match */

// ---------------- workspace layout (bytes) ----------------
// match:       0          .. 2235392   (B*A int32)
// n_pos:       2235392    .. 2235648   (B int32)
// all_neg:     2235648    .. 4471040   (B*A float)
// partials:    4471040    .. 4480000   (B*NTB float)
// batch_total: 4506112    .. 4506368   (B float)
// bestp:       4506368    .. 4514560   (B*G int32)

typedef __attribute__((address_space(3))) unsigned int lds_u32;
typedef const __attribute__((address_space(1))) unsigned int glb_u32;

__device__ __forceinline__ float smoothl1(float d) {
  float ad = fabsf(d);
  return ad < 1.0f ? 0.5f * d * d : ad - 0.5f;
}

__device__ __forceinline__ float frcp(float x) {
  return __builtin_amdgcn_rcpf(x);
}

// Fused matcher. grid (NAB+GG, B), 256 threads.
__global__ __launch_bounds__(256) void k_match(
    const float* __restrict__ anchors, const float* __restrict__ gt_boxes,
    const int* __restrict__ gt_counts, int* __restrict__ match,
    int* __restrict__ bestp, int* __restrict__ n_pos)
{
  const int b = blockIdx.y;
  const int count = gt_counts[b];
  __shared__ float gx0[GG], gy0[GG], gx1[GG], gy1[GG], gar[GG];
  __shared__ float wv[4];
  __shared__ int wi[4];

  if (blockIdx.x < NAB) {
    if (blockIdx.x == 0 && threadIdx.x == 0) n_pos[b] = 0;
    if (threadIdx.x < GG) {
      float4 gb = reinterpret_cast<const float4*>(gt_boxes)[b * GG + threadIdx.x];
      float x0 = gb.x - gb.z * 0.5f, y0 = gb.y - gb.w * 0.5f;
      float x1 = gb.x + gb.z * 0.5f, y1 = gb.y + gb.w * 0.5f;
      gx0[threadIdx.x] = x0; gy0[threadIdx.x] = y0;
      gx1[threadIdx.x] = x1; gy1[threadIdx.x] = y1;
      gar[threadIdx.x] = (x1 - x0) * (y1 - y0);
    }
    __syncthreads();
    const int a = blockIdx.x * 256 + threadIdx.x;
    if (a >= AA) return;

    float4 an = reinterpret_cast<const float4*>(anchors)[a];
    float ax0 = an.x - an.z * 0.5f, ay0 = an.y - an.w * 0.5f;
    float ax1 = an.x + an.z * 0.5f, ay1 = an.y + an.w * 0.5f;
    float aar = (ax1 - ax0) * (ay1 - ay0);
    float best = -1.0f; int bi = 0;
    for (int g = 0; g < count; ++g) {
      float iw = fmaxf(fminf(gx1[g], ax1) - fmaxf(gx0[g], ax0), 0.0f);
      float ih = fmaxf(fminf(gy1[g], ay1) - fmaxf(gy0[g], ay0), 0.0f);
      float inter = iw * ih;
      float iou = inter * frcp(gar[g] + aar - inter);
      if (iou > best) { best = iou; bi = g; }   // first max wins
    }
    match[b * AA + a] = (best > 0.5f) ? bi : -1;
  } else {
    const int g = blockIdx.x - NAB;
    if (g >= count) return;

    float4 gb = reinterpret_cast<const float4*>(gt_boxes)[b * GG + g];
    const float gx0s = gb.x - gb.z * 0.5f, gy0s = gb.y - gb.w * 0.5f;
    const float gx1s = gb.x + gb.z * 0.5f, gy1s = gb.y + gb.w * 0.5f;
    const float gars = (gx1s - gx0s) * (gy1s - gy0s);

    float bv = -2.0f; int bi = AA;
    for (int a = threadIdx.x; a < AA; a += 256) {
      float4 an = reinterpret_cast<const float4*>(anchors)[a];
      float ax0 = an.x - an.z * 0.5f, ay0 = an.y - an.w * 0.5f;
      float ax1 = an.x + an.z * 0.5f, ay1 = an.y + an.w * 0.5f;
      float aar = (ax1 - ax0) * (ay1 - ay0);
      float iw = fmaxf(fminf(gx1s, ax1) - fmaxf(gx0s, ax0), 0.0f);
      float ih = fmaxf(fminf(gy1s, ay1) - fmaxf(gy0s, ay0), 0.0f);
      float inter = iw * ih;
      float iou = inter * frcp(gars + aar - inter);
      if (iou > bv || (iou == bv && a < bi)) { bv = iou; bi = a; }
    }
    #pragma unroll
    for (int m = 1; m < 64; m <<= 1) {
      float ov = __shfl_xor(bv, m);
      int   oi = __shfl_xor(bi, m);
      if (ov > bv || (ov == bv && oi < bi)) { bv = ov; bi = oi; }
    }
    if ((threadIdx.x & 63) == 0) { wv[threadIdx.x >> 6] = bv; wi[threadIdx.x >> 6] = bi; }
    __syncthreads();
    if (threadIdx.x == 0) {
      float fv = wv[0]; int fi = wi[0];
      #pragma unroll
      for (int w = 1; w < 4; ++w)
        if (wv[w] > fv || (wv[w] == fv && wi[w] < fi)) { fv = wv[w]; fi = wi[w]; }
      bestp[b * GG + g] = fi;
    }
  }
}

// Heavy pass v2: grid (NTB, B), 256 threads. Each block sweeps TPB=4 tiles
// with register-staged prefetch: issue next tile's global loads into regs
// at iteration top (pinned by sched_barrier), compute current tile from LDS,
// then barrier -> ds_write regs -> barrier. HBM stays fed during compute
// (breaks the stage/compute convoy).
__global__ __launch_bounds__(256) void k_loss(
    const float* __restrict__ pred, const float* __restrict__ anchors,
    const float* __restrict__ gt_boxes, const int* __restrict__ gt_labels,
    const int* __restrict__ gt_counts, const int* __restrict__ match,
    const int* __restrict__ bestp, float* __restrict__ all_neg,
    float* __restrict__ partials, int* __restrict__ n_pos)
{
  const int b = blockIdx.y;
  const int t0 = blockIdx.x * TPB;
  const int t1 = min(t0 + TPB, NT);
  __shared__ float rows[TILE * DD];
  __shared__ int sbp[GG];
  __shared__ int slab[GG];
  __shared__ float wsum[4];
  __shared__ int wcnt[4];

  const int count = gt_counts[b];
  if (threadIdx.x < GG) {
    sbp[threadIdx.x]  = bestp[b * GG + threadIdx.x];
    slab[threadIdx.x] = gt_labels[b * GG + threadIdx.x];
  }

  uint4 st0, st1, st2, st3, st4, st5;
  int stn = 0;   // chunk count of the staged tile

  // ---- stage tile t into regs (async; caller pins with sched_barrier) ----
  #define STAGE_LOAD(t)                                                      \
    do {                                                                     \
      const int a0_ = (t) * TILE;                                            \
      const int nr_ = min(TILE, AA - a0_);                                   \
      stn = (nr_ * DD) >> 2;                                                 \
      const uint4* s_ = reinterpret_cast<const uint4*>(                      \
          pred + ((size_t)b * AA + a0_) * DD);                               \
      int c_ = threadIdx.x;                                                  \
      if (c_ < stn) st0 = s_[c_]; c_ += 256;                                 \
      if (c_ < stn) st1 = s_[c_]; c_ += 256;                                 \
      if (c_ < stn) st2 = s_[c_]; c_ += 256;                                 \
      if (c_ < stn) st3 = s_[c_]; c_ += 256;                                 \
      if (c_ < stn) st4 = s_[c_]; c_ += 256;                                 \
      if (c_ < stn) st5 = s_[c_];                                            \
    } while (0)

  #define STAGE_WRITE()                                                      \
    do {                                                                     \
      uint4* d_ = reinterpret_cast<uint4*>(rows);                            \
      int c_ = threadIdx.x;                                                  \
      if (c_ < stn) d_[c_] = st0; c_ += 256;                                 \
      if (c_ < stn) d_[c_] = st1; c_ += 256;                                 \
      if (c_ < stn) d_[c_] = st2; c_ += 256;                                 \
      if (c_ < stn) d_[c_] = st3; c_ += 256;                                 \
      if (c_ < stn) d_[c_] = st4; c_ += 256;                                 \
      if (c_ < stn) d_[c_] = st5;                                            \
    } while (0)

  // prologue
  STAGE_LOAD(t0);
  STAGE_WRITE();
  __syncthreads();

  const int r = threadIdx.x >> 2;
  const int sub = threadIdx.x & 3;
  float acc = 0.0f;
  int poscnt = 0;

  for (int t = t0; t < t1; ++t) {
    const int a0 = t * TILE;
    const int nr = min(TILE, AA - a0);
    const bool more = (t + 1 < t1);
    if (more) {
      STAGE_LOAD(t + 1);
      __builtin_amdgcn_sched_barrier(0);   // pin load issue before compute
    }

    if (r < nr) {
      const int a = a0 + r;
      int m = match[b * AA + a];
      for (int g = 0; g < count; ++g)
        m = (sbp[g] == a) ? g : m;          // ascending g = last-write-wins

      const float* row = rows + r * DD + 4;
      float v[21];
      float mx = -INFINITY;
      #pragma unroll
      for (int k = 0; k < 21; ++k) {
        const int cc = 4 * k + sub;
        float x = (cc < CC) ? row[cc] : -INFINITY;
        v[k] = x;
        mx = fmaxf(mx, x);
      }
      #pragma unroll
      for (int msk = 1; msk <= 2; msk <<= 1)
        mx = fmaxf(mx, __shfl_xor(mx, msk));
      float s = 0.0f;
      #pragma unroll
      for (int k = 0; k < 21; ++k) s += __expf(v[k] - mx);  // exp(-inf)=0 pads
      #pragma unroll
      for (int msk = 1; msk <= 2; msk <<= 1) s += __shfl_xor(s, msk);
      const float lse = mx + __logf(s);

      if (sub == 0) {
        if (m >= 0) {
          poscnt += 1;
          const int tgt = slab[m] + 1;
          float cls_ce = lse - row[tgt];
          float4 an = reinterpret_cast<const float4*>(anchors)[a];
          float4 gb = reinterpret_cast<const float4*>(gt_boxes)[b * GG + m];
          float tx = (gb.x - an.x) / an.z;
          float ty = (gb.y - an.y) / an.w;
          float tw = __logf(gb.z) - __logf(an.z);
          float th = __logf(gb.w) - __logf(an.w);
          acc += smoothl1(rows[r * DD + 0] - tx)
               + smoothl1(rows[r * DD + 1] - ty)
               + smoothl1(rows[r * DD + 2] - tw)
               + smoothl1(rows[r * DD + 3] - th)
               + cls_ce;
          all_neg[b * AA + a] = 0.0f;
        } else {
          float ce = lse - row[0];          // tgt==0 for negatives
          all_neg[b * AA + a] = fmaxf(ce, 0.0f);
        }
      }
    }

    if (more) {
      __syncthreads();    // all reads of rows done (drains prefetch too — latency already hidden)
      STAGE_WRITE();
      __syncthreads();    // writes visible
    }
  }

  #pragma unroll
  for (int msk = 1; msk < 64; msk <<= 1) {
    acc    += __shfl_xor(acc, msk);
    poscnt += __shfl_xor(poscnt, msk);
  }
  if ((threadIdx.x & 63) == 0) {
    wsum[threadIdx.x >> 6] = acc;
    wcnt[threadIdx.x >> 6] = poscnt;
  }
  __syncthreads();
  if (threadIdx.x == 0) {
    partials[b * NTB + blockIdx.x] = (wsum[0] + wsum[1]) + (wsum[2] + wsum[3]);
    int c = wcnt[0] + wcnt[1] + wcnt[2] + wcnt[3];
    if (c) atomicAdd(&n_pos[b], c);        // integer add: order-independent
  }
  #undef STAGE_LOAD
  #undef STAGE_WRITE
}

// ---- per-batch top-K sum via 4-round radix select (exact K-th largest) ----
__global__ __launch_bounds__(1024) void k_select(
    const float* __restrict__ all_neg, const float* __restrict__ partials,
    const int* __restrict__ n_pos, float* __restrict__ batch_total)
{
  const int b = blockIdx.x;
  __shared__ unsigned u[AA];           // 34928 B
  __shared__ int hist16[16][257];      // per-wave histograms
  __shared__ int hist[256];
  __shared__ int gsum[64];
  __shared__ unsigned sh_pref;
  __shared__ int sh_k;
  __shared__ float wf[16];
  __shared__ int wc[16];

  {
    const float* srcg = all_neg + (size_t)b * AA;   // 16B-aligned
    #pragma unroll
    for (int j = 0; j < 3; ++j) {
      int c = j * 1024 + threadIdx.x;
      if (c < 2183) {
        __builtin_amdgcn_global_load_lds(
            (glb_u32*)(srcg + c * 4), (lds_u32*)((float*)u + c * 4), 16, 0, 0);
      }
    }
  }
  __syncthreads();

  const int np = n_pos[b];
  const int K = min(3 * np, AA - 1);
  const int wvid = threadIdx.x >> 6;

  unsigned prefix = 0;
  int kk = K;
  for (int shift = 24; shift >= 0; shift -= 8) {
    int* hflat = &hist16[0][0];
    for (int i = threadIdx.x; i < 16 * 257; i += 1024) hflat[i] = 0;
    __syncthreads();
    const unsigned hmask = (shift == 24) ? 0u : (0xFFFFFFFFu << (shift + 8));
    for (int i = threadIdx.x; i < AA; i += 1024) {
      unsigned x = u[i];
      if ((x & hmask) == prefix)
        atomicAdd(&hist16[wvid][(x >> shift) & 255], 1);
    }
    __syncthreads();
    if (threadIdx.x < 256) {
      int s = 0;
      #pragma unroll
      for (int h = 0; h < 16; ++h) s += hist16[h][threadIdx.x];
      hist[threadIdx.x] = s;
    }
    __syncthreads();
    if (threadIdx.x < 64) {
      int base = 255 - 4 * threadIdx.x;
      gsum[threadIdx.x] = hist[base] + hist[base - 1] + hist[base - 2] + hist[base - 3];
    }
    __syncthreads();
    if (threadIdx.x == 0) {
      int cum = 0, chosen = 0;
      const int kv = kk;
      for (int t = 0; t < 64; ++t) {
        int gs = gsum[t];
        if (cum + gs < kv) { cum += gs; continue; }
        for (int bin = 255 - 4 * t; bin >= 252 - 4 * t; --bin) {
          int h = hist[bin];
          if (cum + h >= kv) { chosen = bin; break; }
          cum += h;
        }
        break;
      }
      sh_pref = prefix | ((unsigned)chosen << shift);
      sh_k = kk - cum;
    }
    __syncthreads();
    prefix = sh_pref;
    kk = sh_k;
    __syncthreads();
  }
  const float tstar = __uint_as_float(prefix);   // exact K-th largest

  float ssum = 0.0f; int cgt = 0;
  for (int i = threadIdx.x; i < AA; i += 1024) {
    float x = __uint_as_float(u[i]);
    if (x > tstar) { ssum += x; cgt += 1; }
  }
  #pragma unroll
  for (int m = 1; m < 64; m <<= 1) {
    ssum += __shfl_xor(ssum, m);
    cgt  += __shfl_xor(cgt, m);
  }
  if ((threadIdx.x & 63) == 0) { wf[wvid] = ssum; wc[wvid] = cgt; }
  __syncthreads();
  if (threadIdx.x == 0) {
    float S = 0.0f; int Cg = 0;
    for (int w = 0; w < 16; ++w) { S += wf[w]; Cg += wc[w]; }
    float neg_sum = S + (float)(K - Cg) * tstar;
    float ps = 0.0f;
    for (int t = 0; t < NTB; ++t) ps += partials[b * NTB + t];
    batch_total[b] = (ps + neg_sum) / (float)np;
  }
}

__global__ __launch_bounds__(64) void k_final(
    const float* __restrict__ batch_total, float* __restrict__ out)
{
  float v = batch_total[threadIdx.x];   // BB == 64 == one wave
  #pragma unroll
  for (int m = 1; m < 64; m <<= 1) v += __shfl_xor(v, m);
  if (threadIdx.x == 0) out[0] = v;
}

extern "C" void kernel_launch(void* const* d_in, const int* in_sizes, int n_in,
                              void* d_out, int out_size, void* d_ws, size_t ws_size,
                              hipStream_t stream) {
  (void)in_sizes; (void)n_in; (void)out_size; (void)ws_size;
  const float* pred      = (const float*)d_in[0];
  const float* anchors   = (const float*)d_in[1];
  const float* gt_boxes  = (const float*)d_in[2];
  const int*   gt_labels = (const int*)d_in[3];
  const int*   gt_counts = (const int*)d_in[4];

  char* ws = (char*)d_ws;
  int*   match       = (int*)(ws + 0);
  int*   n_pos       = (int*)(ws + 2235392);
  float* all_neg     = (float*)(ws + 2235648);
  float* partials    = (float*)(ws + 4471040);
  float* batch_total = (float*)(ws + 4506112);
  int*   bestp       = (int*)(ws + 4506368);
  float* out = (float*)d_out;

  hipLaunchKernelGGL(k_match, dim3(NAB + GG, BB), dim3(256), 0, stream,
                     anchors, gt_boxes, gt_counts, match, bestp, n_pos);
  hipLaunchKernelGGL(k_loss, dim3(NTB, BB), dim3(256), 0, stream,
                     pred, anchors, gt_boxes, gt_labels, gt_counts, match, bestp,
                     all_neg, partials, n_pos);
  hipLaunchKernelGGL(k_select, dim3(BB), dim3(1024), 0, stream,
                     all_neg, partials, n_pos, batch_total);
  hipLaunchKernelGGL(k_final, dim3(1), dim3(64), 0, stream, batch_total, out);
}

// Round 7
// 97.051 us; speedup vs baseline: 1.5480x; 1.0435x over previous
//
#include <hip/hip_runtime.h>
#include <math.h>

#define BB 64
#define AA 8732
#define DD 85
#define GG 32
#define CC 81
#define TILE 64
#define NT 137   /* ceil(8732/64) tiles */
#define TPB 12   /* tiles per k_loss block */
#define NTB 12   /* ceil(NT/TPB) = k_loss grid.x ; 768 blocks = 3/CU resident */
#define NAB 35   /* ceil(8732/256) stage-A blocks in k_match */

// ---------------- workspace layout (bytes) ----------------
// match:       0          .. 2235392   (B*A int32)
// n_pos:       2235392    .. 2235648   (B int32)
// all_neg:     2235648    .. 4471040   (B*A float)
// partials:    4471040    .. 4474112   (B*NTB float)
// batch_total: 4506112    .. 4506368   (B float)
// bestp:       4506368    .. 4514560   (B*G int32)

typedef __attribute__((address_space(3))) unsigned int lds_u32;
typedef const __attribute__((address_space(1))) unsigned int glb_u32;

__device__ __forceinline__ float smoothl1(float d) {
  float ad = fabsf(d);
  return ad < 1.0f ? 0.5f * d * d : ad - 0.5f;
}

__device__ __forceinline__ float frcp(float x) {
  return __builtin_amdgcn_rcpf(x);
}

// Fused matcher. grid (NAB+GG, B), 256 threads.
__global__ __launch_bounds__(256) void k_match(
    const float* __restrict__ anchors, const float* __restrict__ gt_boxes,
    const int* __restrict__ gt_counts, int* __restrict__ match,
    int* __restrict__ bestp, int* __restrict__ n_pos)
{
  const int b = blockIdx.y;
  const int count = gt_counts[b];
  __shared__ float gx0[GG], gy0[GG], gx1[GG], gy1[GG], gar[GG];
  __shared__ float wv[4];
  __shared__ int wi[4];

  if (blockIdx.x < NAB) {
    if (blockIdx.x == 0 && threadIdx.x == 0) n_pos[b] = 0;
    if (threadIdx.x < GG) {
      float4 gb = reinterpret_cast<const float4*>(gt_boxes)[b * GG + threadIdx.x];
      float x0 = gb.x - gb.z * 0.5f, y0 = gb.y - gb.w * 0.5f;
      float x1 = gb.x + gb.z * 0.5f, y1 = gb.y + gb.w * 0.5f;
      gx0[threadIdx.x] = x0; gy0[threadIdx.x] = y0;
      gx1[threadIdx.x] = x1; gy1[threadIdx.x] = y1;
      gar[threadIdx.x] = (x1 - x0) * (y1 - y0);
    }
    __syncthreads();
    const int a = blockIdx.x * 256 + threadIdx.x;
    if (a >= AA) return;

    float4 an = reinterpret_cast<const float4*>(anchors)[a];
    float ax0 = an.x - an.z * 0.5f, ay0 = an.y - an.w * 0.5f;
    float ax1 = an.x + an.z * 0.5f, ay1 = an.y + an.w * 0.5f;
    float aar = (ax1 - ax0) * (ay1 - ay0);
    float best = -1.0f; int bi = 0;
    for (int g = 0; g < count; ++g) {
      float iw = fmaxf(fminf(gx1[g], ax1) - fmaxf(gx0[g], ax0), 0.0f);
      float ih = fmaxf(fminf(gy1[g], ay1) - fmaxf(gy0[g], ay0), 0.0f);
      float inter = iw * ih;
      float iou = inter * frcp(gar[g] + aar - inter);
      if (iou > best) { best = iou; bi = g; }   // first max wins
    }
    match[b * AA + a] = (best > 0.5f) ? bi : -1;
  } else {
    const int g = blockIdx.x - NAB;
    if (g >= count) return;

    float4 gb = reinterpret_cast<const float4*>(gt_boxes)[b * GG + g];
    const float gx0s = gb.x - gb.z * 0.5f, gy0s = gb.y - gb.w * 0.5f;
    const float gx1s = gb.x + gb.z * 0.5f, gy1s = gb.y + gb.w * 0.5f;
    const float gars = (gx1s - gx0s) * (gy1s - gy0s);

    float bv = -2.0f; int bi = AA;
    for (int a = threadIdx.x; a < AA; a += 256) {
      float4 an = reinterpret_cast<const float4*>(anchors)[a];
      float ax0 = an.x - an.z * 0.5f, ay0 = an.y - an.w * 0.5f;
      float ax1 = an.x + an.z * 0.5f, ay1 = an.y + an.w * 0.5f;
      float aar = (ax1 - ax0) * (ay1 - ay0);
      float iw = fmaxf(fminf(gx1s, ax1) - fmaxf(gx0s, ax0), 0.0f);
      float ih = fmaxf(fminf(gy1s, ay1) - fmaxf(gy0s, ay0), 0.0f);
      float inter = iw * ih;
      float iou = inter * frcp(gars + aar - inter);
      if (iou > bv || (iou == bv && a < bi)) { bv = iou; bi = a; }
    }
    #pragma unroll
    for (int m = 1; m < 64; m <<= 1) {
      float ov = __shfl_xor(bv, m);
      int   oi = __shfl_xor(bi, m);
      if (ov > bv || (ov == bv && oi < bi)) { bv = ov; bi = oi; }
    }
    if ((threadIdx.x & 63) == 0) { wv[threadIdx.x >> 6] = bv; wi[threadIdx.x >> 6] = bi; }
    __syncthreads();
    if (threadIdx.x == 0) {
      float fv = wv[0]; int fi = wi[0];
      #pragma unroll
      for (int w = 1; w < 4; ++w)
        if (wv[w] > fv || (wv[w] == fv && wi[w] < fi)) { fv = wv[w]; fi = wi[w]; }
      bestp[b * GG + g] = fi;
    }
  }
}

// Tiny: apply forced-match overrides into match[] (ascending g = last-write-wins).
__global__ __launch_bounds__(64) void k_scatter(
    const int* __restrict__ gt_counts, const int* __restrict__ bestp,
    int* __restrict__ match)
{
  const int b = blockIdx.x;
  if (threadIdx.x == 0) {
    const int count = gt_counts[b];
    for (int g = 0; g < count; ++g) match[b * AA + bestp[b * GG + g]] = g;
  }
}

// Heavy pass v3: grid (NTB, B), 256 threads, 4 threads/row.
// Double-buffered LDS + global_load_lds fire-and-forget prefetch: issue next
// tile's direct-to-LDS loads into buf^1, compute current tile from buf, then
// one __syncthreads (its vmcnt(0) drain lands AFTER compute -> loads hidden).
__global__ __launch_bounds__(256) void k_loss(
    const float* __restrict__ pred, const float* __restrict__ anchors,
    const float* __restrict__ gt_boxes, const int* __restrict__ gt_labels,
    const int* __restrict__ match, float* __restrict__ all_neg,
    float* __restrict__ partials, int* __restrict__ n_pos)
{
  const int b = blockIdx.y;
  const int t0 = blockIdx.x * TPB;
  const int t1 = min(t0 + TPB, NT);
  __shared__ float bufs[2][TILE * DD];   // 2 x 21760 B
  __shared__ int slab[GG];
  __shared__ float wsum[4];
  __shared__ int wcnt[4];

  if (threadIdx.x < GG) slab[threadIdx.x] = gt_labels[b * GG + threadIdx.x];

  #define PREFETCH(t, bufp)                                                  \
    do {                                                                     \
      const int a0_ = (t) * TILE;                                            \
      const int nch_ = (min(TILE, AA - a0_) * DD) >> 2;                      \
      const float* s_ = pred + ((size_t)b * AA + a0_) * DD;                  \
      _Pragma("unroll")                                                      \
      for (int j_ = 0; j_ < 6; ++j_) {                                       \
        int c_ = j_ * 256 + (int)threadIdx.x;                                \
        if (c_ < nch_)                                                       \
          __builtin_amdgcn_global_load_lds(                                  \
              (glb_u32*)(s_ + c_ * 4), (lds_u32*)((bufp) + c_ * 4), 16, 0, 0);\
      }                                                                      \
    } while (0)

  PREFETCH(t0, &bufs[0][0]);
  __syncthreads();

  const int r = threadIdx.x >> 2;
  const int sub = threadIdx.x & 3;
  float acc = 0.0f;
  int poscnt = 0;
  int cur = 0;

  for (int t = t0; t < t1; ++t) {
    if (t + 1 < t1) {
      PREFETCH(t + 1, &bufs[cur ^ 1][0]);
      __builtin_amdgcn_sched_barrier(0);   // keep issue ahead of compute
    }

    const int a0 = t * TILE;
    const int nr = min(TILE, AA - a0);
    const float* rows = &bufs[cur][0];

    if (r < nr) {
      const int a = a0 + r;
      const int m = match[b * AA + a];

      const float* row = rows + r * DD + 4;
      float v[21];
      float mx = -INFINITY;
      #pragma unroll
      for (int k = 0; k < 21; ++k) {
        const int cc = 4 * k + sub;
        float x = (cc < CC) ? row[cc] : -INFINITY;
        v[k] = x;
        mx = fmaxf(mx, x);
      }
      #pragma unroll
      for (int msk = 1; msk <= 2; msk <<= 1)
        mx = fmaxf(mx, __shfl_xor(mx, msk));
      float s = 0.0f;
      #pragma unroll
      for (int k = 0; k < 21; ++k) s += __expf(v[k] - mx);  // exp(-inf)=0 pads
      #pragma unroll
      for (int msk = 1; msk <= 2; msk <<= 1) s += __shfl_xor(s, msk);
      const float lse = mx + __logf(s);

      if (sub == 0) {
        if (m >= 0) {
          poscnt += 1;
          const int tgt = slab[m] + 1;
          float cls_ce = lse - row[tgt];
          float4 an = reinterpret_cast<const float4*>(anchors)[a];
          float4 gb = reinterpret_cast<const float4*>(gt_boxes)[b * GG + m];
          float tx = (gb.x - an.x) / an.z;
          float ty = (gb.y - an.y) / an.w;
          float tw = __logf(gb.z) - __logf(an.z);
          float th = __logf(gb.w) - __logf(an.w);
          acc += smoothl1(rows[r * DD + 0] - tx)
               + smoothl1(rows[r * DD + 1] - ty)
               + smoothl1(rows[r * DD + 2] - tw)
               + smoothl1(rows[r * DD + 3] - th)
               + cls_ce;
          all_neg[b * AA + a] = 0.0f;
        } else {
          float ce = lse - row[0];          // tgt==0 for negatives
          all_neg[b * AA + a] = fmaxf(ce, 0.0f);
        }
      }
    }

    __syncthreads();   // vmcnt(0) drain (prefetch landed) + reads done
    cur ^= 1;
  }

  #pragma unroll
  for (int msk = 1; msk < 64; msk <<= 1) {
    acc    += __shfl_xor(acc, msk);
    poscnt += __shfl_xor(poscnt, msk);
  }
  if ((threadIdx.x & 63) == 0) {
    wsum[threadIdx.x >> 6] = acc;
    wcnt[threadIdx.x >> 6] = poscnt;
  }
  __syncthreads();
  if (threadIdx.x == 0) {
    partials[b * NTB + blockIdx.x] = (wsum[0] + wsum[1]) + (wsum[2] + wsum[3]);
    int c = wcnt[0] + wcnt[1] + wcnt[2] + wcnt[3];
    if (c) atomicAdd(&n_pos[b], c);        // integer add: order-independent
  }
  #undef PREFETCH
}

// ---- per-batch top-K sum via 4-round radix select (exact K-th largest) ----
__global__ __launch_bounds__(1024) void k_select(
    const float* __restrict__ all_neg, const float* __restrict__ partials,
    const int* __restrict__ n_pos, float* __restrict__ batch_total)
{
  const int b = blockIdx.x;
  __shared__ unsigned u[AA];           // 34928 B
  __shared__ int hist16[16][257];      // per-wave histograms
  __shared__ int hist[256];
  __shared__ int gsum[64];
  __shared__ unsigned sh_pref;
  __shared__ int sh_k;
  __shared__ float wf[16];
  __shared__ int wc[16];

  {
    const float* srcg = all_neg + (size_t)b * AA;   // 16B-aligned
    #pragma unroll
    for (int j = 0; j < 3; ++j) {
      int c = j * 1024 + threadIdx.x;
      if (c < 2183) {
        __builtin_amdgcn_global_load_lds(
            (glb_u32*)(srcg + c * 4), (lds_u32*)((float*)u + c * 4), 16, 0, 0);
      }
    }
  }
  __syncthreads();

  const int np = n_pos[b];
  const int K = min(3 * np, AA - 1);
  const int wvid = threadIdx.x >> 6;

  unsigned prefix = 0;
  int kk = K;
  for (int shift = 24; shift >= 0; shift -= 8) {
    int* hflat = &hist16[0][0];
    for (int i = threadIdx.x; i < 16 * 257; i += 1024) hflat[i] = 0;
    __syncthreads();
    const unsigned hmask = (shift == 24) ? 0u : (0xFFFFFFFFu << (shift + 8));
    for (int i = threadIdx.x; i < AA; i += 1024) {
      unsigned x = u[i];
      if ((x & hmask) == prefix)
        atomicAdd(&hist16[wvid][(x >> shift) & 255], 1);
    }
    __syncthreads();
    if (threadIdx.x < 256) {
      int s = 0;
      #pragma unroll
      for (int h = 0; h < 16; ++h) s += hist16[h][threadIdx.x];
      hist[threadIdx.x] = s;
    }
    __syncthreads();
    if (threadIdx.x < 64) {
      int base = 255 - 4 * threadIdx.x;
      gsum[threadIdx.x] = hist[base] + hist[base - 1] + hist[base - 2] + hist[base - 3];
    }
    __syncthreads();
    if (threadIdx.x == 0) {
      int cum = 0, chosen = 0;
      const int kv = kk;
      for (int t = 0; t < 64; ++t) {
        int gs = gsum[t];
        if (cum + gs < kv) { cum += gs; continue; }
        for (int bin = 255 - 4 * t; bin >= 252 - 4 * t; --bin) {
          int h = hist[bin];
          if (cum + h >= kv) { chosen = bin; break; }
          cum += h;
        }
        break;
      }
      sh_pref = prefix | ((unsigned)chosen << shift);
      sh_k = kk - cum;
    }
    __syncthreads();
    prefix = sh_pref;
    kk = sh_k;
    __syncthreads();
  }
  const float tstar = __uint_as_float(prefix);   // exact K-th largest

  float ssum = 0.0f; int cgt = 0;
  for (int i = threadIdx.x; i < AA; i += 1024) {
    float x = __uint_as_float(u[i]);
    if (x > tstar) { ssum += x; cgt += 1; }
  }
  #pragma unroll
  for (int m = 1; m < 64; m <<= 1) {
    ssum += __shfl_xor(ssum, m);
    cgt  += __shfl_xor(cgt, m);
  }
  if ((threadIdx.x & 63) == 0) { wf[wvid] = ssum; wc[wvid] = cgt; }
  __syncthreads();
  if (threadIdx.x == 0) {
    float S = 0.0f; int Cg = 0;
    for (int w = 0; w < 16; ++w) { S += wf[w]; Cg += wc[w]; }
    float neg_sum = S + (float)(K - Cg) * tstar;
    float ps = 0.0f;
    for (int t = 0; t < NTB; ++t) ps += partials[b * NTB + t];
    batch_total[b] = (ps + neg_sum) / (float)np;
  }
}

__global__ __launch_bounds__(64) void k_final(
    const float* __restrict__ batch_total, float* __restrict__ out)
{
  float v = batch_total[threadIdx.x];   // BB == 64 == one wave
  #pragma unroll
  for (int m = 1; m < 64; m <<= 1) v += __shfl_xor(v, m);
  if (threadIdx.x == 0) out[0] = v;
}

extern "C" void kernel_launch(void* const* d_in, const int* in_sizes, int n_in,
                              void* d_out, int out_size, void* d_ws, size_t ws_size,
                              hipStream_t stream) {
  (void)in_sizes; (void)n_in; (void)out_size; (void)ws_size;
  const float* pred      = (const float*)d_in[0];
  const float* anchors   = (const float*)d_in[1];
  const float* gt_boxes  = (const float*)d_in[2];
  const int*   gt_labels = (const int*)d_in[3];
  const int*   gt_counts = (const int*)d_in[4];

  char* ws = (char*)d_ws;
  int*   match       = (int*)(ws + 0);
  int*   n_pos       = (int*)(ws + 2235392);
  float* all_neg     = (float*)(ws + 2235648);
  float* partials    = (float*)(ws + 4471040);
  float* batch_total = (float*)(ws + 4506112);
  int*   bestp       = (int*)(ws + 4506368);
  float* out = (float*)d_out;

  hipLaunchKernelGGL(k_match, dim3(NAB + GG, BB), dim3(256), 0, stream,
                     anchors, gt_boxes, gt_counts, match, bestp, n_pos);
  hipLaunchKernelGGL(k_scatter, dim3(BB), dim3(64), 0, stream,
                     gt_counts, bestp, match);
  hipLaunchKernelGGL(k_loss, dim3(NTB, BB), dim3(256), 0, stream,
                     pred, anchors, gt_boxes, gt_labels, match,
                     all_neg, partials, n_pos);
  hipLaunchKernelGGL(k_select, dim3(BB), dim3(1024), 0, stream,
                     all_neg, partials, n_pos, batch_total);
  hipLaunchKernelGGL(k_final, dim3(1), dim3(64), 0, stream, batch_total, out);
}